// Round 10
// baseline (164.984 us; speedup 1.0000x reference)
//
#include <hip/hip_runtime.h>
#include <hip/hip_bf16.h>

typedef __attribute__((ext_vector_type(8))) short short8;
typedef __attribute__((ext_vector_type(4))) float f32x4;
typedef __attribute__((ext_vector_type(16))) float f32x16;
typedef unsigned short u16;
typedef unsigned int u32;

// ---------------- workspace layout (bytes) ----------------
#define OFF_XT      0u          // x NHWC bf16: 4*64*64*256 = 8388608 B
#define OFF_OM      8388608u    // offsets fp32: 16384*32*4  = 2097152 B
#define OFF_Y       10485760u   // mdcn out NHWC bf16: 16384*128*2 = 4194304 B
#define OFF_Y2      14680064u   // deconv out NCHW bf16: 4*128*128*128*2 = 16777216 B
#define OFF_BOFF    31457280u   // Boff16 [72][2][64][8] bf16 = 147456 B
#define OFF_BDCN    31604736u   // Bdcn16 [72][8][64][8] bf16 = 589824 B
#define OFF_BUP     32194560u   // Bup'  [4][32][4][2][32][8] bf16 = 524288 B
#define OFF_P1      32718848u   // BN1 partials [32 slice][256] f32 = 32768 B
#define OFF_P2      32751616u   // BN2 partials [32 slice][256] f32 = 32768 B
// end: 32784384 B

__device__ __forceinline__ float lo2f(u32 u){ u32 v = u << 16; float f; __builtin_memcpy(&f, &v, 4); return f; }
__device__ __forceinline__ float hi2f(u32 u){ u32 v = u & 0xffff0000u; float f; __builtin_memcpy(&f, &v, 4); return f; }
__device__ __forceinline__ float b2f(u16 v){ u32 u = ((u32)v) << 16; float f; __builtin_memcpy(&f, &u, 4); return f; }
__device__ __forceinline__ u16 f2b(float f){ __hip_bfloat16 h = __float2bfloat16(f); u16 r; __builtin_memcpy(&r, &h, 2); return r; }
// fast RNE f32->bf16 (finite values only)
__device__ __forceinline__ u32 rne(float f){ u32 u; __builtin_memcpy(&u, &f, 4); return u + 0x7FFFu + ((u >> 16) & 1u); }
__device__ __forceinline__ u32 pk2(float f0, float f1){ return (rne(f0) >> 16) | (rne(f1) & 0xFFFF0000u); }

__device__ __forceinline__ f32x4 mfma16(short8 a, short8 b, f32x4 c){
  return __builtin_amdgcn_mfma_f32_16x16x32_bf16(a, b, c, 0, 0, 0);
}
__device__ __forceinline__ f32x16 mfma32(short8 a, short8 b, f32x16 c){
  return __builtin_amdgcn_mfma_f32_32x32x16_bf16(a, b, c, 0, 0, 0);
}
__device__ __forceinline__ void unpk(uint4 u, float* f){
  f[0]=lo2f(u.x); f[1]=hi2f(u.x); f[2]=lo2f(u.y); f[3]=hi2f(u.y);
  f[4]=lo2f(u.z); f[5]=hi2f(u.z); f[6]=lo2f(u.w); f[7]=hi2f(u.w);
}
__device__ __forceinline__ uint4 pk8(const float* f){
  uint4 r;
  r.x = pk2(f[0], f[1]); r.y = pk2(f[2], f[3]);
  r.z = pk2(f[4], f[5]); r.w = pk2(f[6], f[7]);
  return r;
}
// XCD-chunked bijective swizzle for 1024-block grids (1024 % 8 == 0):
// each XCD gets 128 CONSECUTIVE logical tiles -> halo rows shared within one L2.
__device__ __forceinline__ int xcd_swz(int blk0){ return ((blk0 & 7) << 7) | (blk0 >> 3); }

// ---------------- kernel 1: weight reorg + transpose + partials-zero (one dispatch) ----------------
__global__ __launch_bounds__(256) void prep_transpose_kernel(const float* __restrict__ x,
                                                             u16* __restrict__ xt,
                                                             const float* __restrict__ w_off,
                                                             const float* __restrict__ w_dcn,
                                                             const float* __restrict__ w_up,
                                                             u16* __restrict__ Boff,
                                                             u16* __restrict__ Bdcn,
                                                             u16* __restrict__ Bup,
                                                             float* __restrict__ pz){
  __shared__ u16 Ls[64][65];
  int blk = blockIdx.x;
  int t = threadIdx.x;
  if (blk >= 2176){
    // ---- zero BN partials p1+p2 (16384 f32 = 4096 float4) ----
    float4* p4 = (float4*)pz;
    #pragma unroll
    for (int i = 0; i < 16; i++)
      p4[t*16 + i] = make_float4(0.f, 0.f, 0.f, 0.f);
    return;
  }
  if (blk < 1024){
    // ---- transpose: 1024 = 4b * 64h * 4cb; float4 reads, uint2 writes (G13) ----
    int cb = blk & 3, h = (blk >> 2) & 63, b = blk >> 8;
    int c0 = cb * 64;
    {
      int w4 = (t & 15) * 4;
      #pragma unroll
      for (int i = 0; i < 4; i++){
        int c = (t >> 4) + 16*i;
        float4 v = *(const float4*)(x + (((b*256 + c0 + c)*64 + h)*64 + w4));
        Ls[c][w4+0] = f2b(v.x);
        Ls[c][w4+1] = f2b(v.y);
        Ls[c][w4+2] = f2b(v.z);
        Ls[c][w4+3] = f2b(v.w);
      }
    }
    __syncthreads();
    #pragma unroll
    for (int i = 0; i < 4; i++){
      int idx = t + i*256;
      int w = idx >> 4, cc = (idx & 15) * 4;
      u32 a0 = Ls[cc+0][w], a1 = Ls[cc+1][w];
      u32 a2 = Ls[cc+2][w], a3 = Ls[cc+3][w];
      uint2 val = make_uint2(a0 | (a1 << 16), a2 | (a3 << 16));
      *(uint2*)(xt + (((b*64 + h)*64 + w) << 8) + c0 + cc) = val;
    }
    return;
  }
  // ---- prep: 1152 blocks ----
  int i = (blk - 1024) * 256 + t;
  if (i < 72*2*64*8){
    int j = i & 7, lane = (i >> 3) & 63, nt = (i >> 9) & 1, kc = i >> 10;
    int n = nt*16 + (lane & 15);
    int k = kc*32 + ((lane >> 4) & 3)*8 + j, tap = k >> 8, c = k & 255;
    int ky = tap / 3, kx = tap - ky*3;
    u16 v = 0;
    if (n < 27) v = f2b(w_off[((n*256 + c)*3 + ky)*3 + kx]);
    Boff[i] = v;
  }
  if (i < 72*8*64*8){
    int j = i & 7, lane = (i >> 3) & 63, nt = (i >> 9) & 7, kc = i >> 12;
    int o = nt*16 + (lane & 15);
    int k = kc*32 + ((lane >> 4) & 3)*8 + j, tap = k >> 8, c = k & 255;
    int ky = tap / 3, kx = tap - ky*3;
    Bdcn[i] = f2b(w_dcn[((o*256 + c)*3 + ky)*3 + kx]);
  }
  if (i < 4*32*4*2*32*8){
    int j = i & 7, n = (i >> 3) & 31, kh = (i >> 8) & 1, a4 = (i >> 9) & 3;
    int kc = (i >> 11) & 31, pp = i >> 16;
    int k = kc*16 + kh*8 + j, tapd = k >> 7, c = k & 127;
    int o = a4*32 + n;
    int py = pp >> 1, px = pp & 1, dy = tapd >> 1, dx = tapd & 1;
    Bup[i] = f2b(w_up[((c*128 + o)*4 + (3-(py+2*dy)))*4 + (3-(px+2*dx))]);
  }
}

// ---------------- stage 1: offset conv; dbuf 3-phase pipeline, 4-wave K-split ----------------
// lb(256,4): grid=1024 -> 4 blocks/CU grid-capped; old (256,8) capped VGPR at 64 for an
// occupancy that can never materialize. 128-cap frees the staging/B-fragment pipeline.
__global__ __launch_bounds__(256, 4) void convoff_kernel(const u16* __restrict__ xt,
                                                         const u16* __restrict__ Boff,
                                                         const float* __restrict__ b_off,
                                                         float* __restrict__ om){
  __shared__ alignas(16) char smem[16896];    // As dbuf 2x[16px][264]; Ys overlays
  u16* As0 = (u16*)smem;
  u16* As1 = (u16*)(smem + 8448);
  float* Ys = (float*)smem;                   // [4][16][36] = 9216 B (after final barrier)
  int blk = xcd_swz(blockIdx.x);        // 1024 = 4b * 64h * 4wt (XCD-chunked)
  int wt = blk & 3, h = (blk >> 2) & 63, b = blk >> 8;
  int w0 = wt * 16;
  int P0 = (b*64 + h)*64 + w0;
  int t = threadIdx.x;
  int wv = t >> 6, lane = t & 63;
  int ln = lane & 15, q4 = (lane >> 4) & 3;
  int spx = t >> 5, sc16a = t & 31;     // staging: px = spx(+8), c16
  f32x4 acc[2];
  acc[0] = (f32x4){0.f,0.f,0.f,0.f};
  acc[1] = (f32x4){0.f,0.f,0.f,0.f};
  uint4 pf[2];

  // prefetch + stage tap 0
  {
    int ky = -1, kx = -1;
    #pragma unroll
    for (int it = 0; it < 2; it++){
      int px = spx + it*8;
      int y = h + ky, xw = w0 + px + kx;
      pf[it] = make_uint4(0,0,0,0);
      if ((u32)y < 64u && (u32)xw < 64u)
        pf[it] = *(const uint4*)(xt + (((b*64 + y)*64 + xw) << 8) + sc16a*8);
    }
    #pragma unroll
    for (int it = 0; it < 2; it++)
      *(uint4*)(As0 + (spx + it*8)*264 + sc16a*8) = pf[it];
  }
  __syncthreads();

  for (int tap = 0; tap < 9; tap++){
    const u16* cur = (tap & 1) ? As1 : As0;
    u16* nxt = (tap & 1) ? As0 : As1;
    if (tap < 8){
      int tn = tap + 1;
      int ky = tn/3 - 1, kx = tn - (tn/3)*3 - 1;
      #pragma unroll
      for (int it = 0; it < 2; it++){
        int px = spx + it*8;
        int y = h + ky, xw = w0 + px + kx;
        pf[it] = make_uint4(0,0,0,0);
        if ((u32)y < 64u && (u32)xw < 64u)
          pf[it] = *(const uint4*)(xt + (((b*64 + y)*64 + xw) << 8) + sc16a*8);
      }
    }
    #pragma unroll
    for (int q = 0; q < 2; q++){
      int kcl = wv*2 + q;
      int kcg = tap*8 + kcl;
      short8 a = *(const short8*)(cur + ln*264 + kcl*32 + q4*8);
      #pragma unroll
      for (int nt = 0; nt < 2; nt++){
        short8 bb = *(const short8*)(Boff + ((kcg*2 + nt)*64 + lane)*8);
        acc[nt] = mfma16(a, bb, acc[nt]);
      }
    }
    if (tap < 8){
      #pragma unroll
      for (int it = 0; it < 2; it++)
        *(uint4*)(nxt + (spx + it*8)*264 + sc16a*8) = pf[it];
    }
    __syncthreads();
  }
  // K-split reduction (Ys overlays As; loop's final barrier protects)
  #pragma unroll
  for (int nt = 0; nt < 2; nt++)
    #pragma unroll
    for (int r = 0; r < 4; r++)
      Ys[(wv*16 + q4*4 + r)*36 + nt*16 + ln] = acc[nt][r];
  __syncthreads();
  {
    int px = t >> 4, s = t & 15;
    #pragma unroll
    for (int half = 0; half < 2; half++){
      int n = s + half*16;
      if (n < 27){
        float sum = Ys[(px)*36 + n] + Ys[(16 + px)*36 + n]
                  + Ys[(32 + px)*36 + n] + Ys[(48 + px)*36 + n] + b_off[n];
        om[(P0 + px)*32 + n] = sum;
      }
    }
  }
}

// ---------------- stage 2: mdcn v13: 2-tap-deep gather pipeline, NAMED register sets ----------------
__global__ __launch_bounds__(256, 4) void mdcn_kernel(const u16* __restrict__ xt,
                                                      const float* __restrict__ om,
                                                      const u16* __restrict__ Bdcn,
                                                      const float* __restrict__ b_dcn,
                                                      u16* __restrict__ yb,
                                                      float* __restrict__ p1){
  __shared__ alignas(16) char smem[23552];
  u16* As0 = (u16*)smem;
  u16* As1 = (u16*)(smem + 8448);
  float* Ptab = (float*)(smem + 16896);       // [16 px][9 tap][8]: a00,a01,a10,a11,w00,w01,w10,w11
  u16* Lp = (u16*)(smem + 8448);              // [16][136] epilogue overlay of As1
  float* red = (float*)(smem + 21504);        // [512] stats reduce (disjoint)
  int blk = xcd_swz(blockIdx.x);        // 1024 = 4b * 64h * 4wt (XCD-chunked)
  int wt = blk & 3, h = (blk >> 2) & 63, b = blk >> 8;
  int w0 = wt * 16;
  int P0 = (b*64 + h)*64 + w0;
  int t = threadIdx.x;
  int wv = t >> 6, lane = t & 63;
  int m = lane & 31, kh = lane >> 5;
  int ln = lane & 15, q4 = (lane >> 4) & 3;
  float bias0 = b_dcn[wv*32 + ln];
  float bias1 = b_dcn[wv*32 + 16 + ln];

  // ---- build param table (one thread per (px,tap)) ----
  if (t < 144){
    int px = t / 9, tap = t - (t/9)*9;
    int ky = tap / 3, kx = tap - ky*3;
    const float* omp = om + (P0 + px)*32;
    float dy  = omp[2*tap];
    float dxv = omp[2*tap + 1];
    float mk  = 1.f / (1.f + __expf(-omp[18 + tap]));
    float ys = (float)(h - 1 + ky) + dy;
    float xs = (float)(w0 + px - 1 + kx) + dxv;
    float y0f = floorf(ys), x0f = floorf(xs);
    float ly = ys - y0f, lx = xs - x0f;
    int y0 = (int)y0f, x0 = (int)x0f;
    bool vy0 = (u32)y0 < 64u, vy1 = (u32)(y0+1) < 64u;
    bool vx0 = (u32)x0 < 64u, vx1 = (u32)(x0+1) < 64u;
    int ya = min(max(y0, 0), 63),   ybr_ = min(max(y0+1, 0), 63);
    int xa = min(max(x0, 0), 63),   xb = min(max(x0+1, 0), 63);
    u32 a00 = (u32)(((b*64 + ya)*64 + xa) << 8);
    u32 a01 = (u32)(((b*64 + ya)*64 + xb) << 8);
    u32 a10 = (u32)(((b*64 + ybr_)*64 + xa) << 8);
    u32 a11 = (u32)(((b*64 + ybr_)*64 + xb) << 8);
    float w00 = (vy0 && vx0) ? (1.f-ly)*(1.f-lx)*mk : 0.f;
    float w01 = (vy0 && vx1) ? (1.f-ly)*lx*mk       : 0.f;
    float w10 = (vy1 && vx0) ? ly*(1.f-lx)*mk       : 0.f;
    float w11 = (vy1 && vx1) ? ly*lx*mk             : 0.f;
    float* P = Ptab + t*8;
    ((u32*)P)[0] = a00; ((u32*)P)[1] = a01; ((u32*)P)[2] = a10; ((u32*)P)[3] = a11;
    P[4] = w00; P[5] = w01; P[6] = w10; P[7] = w11;
  }
  __syncthreads();

  f32x4 acc[2];
  acc[0] = (f32x4){0.f,0.f,0.f,0.f};
  acc[1] = (f32x4){0.f,0.f,0.f,0.f};
  uint4 puA[8], puB[8];     // two in-flight gather sets, NAMED (never passed via pointer)
  float4 pwA[2], pwB[2];

  auto prefetchA = [&](int tap){
    #pragma unroll
    for (int i = 0; i < 2; i++){
      int p = wv*4 + i*2 + kh;
      const float* P = Ptab + (p*9 + tap)*8;
      uint4 pa = *(const uint4*)P;
      pwA[i] = *(const float4*)(P + 4);
      puA[i*4+0] = *(const uint4*)(xt + pa.x + m*8);
      puA[i*4+1] = *(const uint4*)(xt + pa.y + m*8);
      puA[i*4+2] = *(const uint4*)(xt + pa.z + m*8);
      puA[i*4+3] = *(const uint4*)(xt + pa.w + m*8);
    }
  };
  auto prefetchB = [&](int tap){
    #pragma unroll
    for (int i = 0; i < 2; i++){
      int p = wv*4 + i*2 + kh;
      const float* P = Ptab + (p*9 + tap)*8;
      uint4 pa = *(const uint4*)P;
      pwB[i] = *(const float4*)(P + 4);
      puB[i*4+0] = *(const uint4*)(xt + pa.x + m*8);
      puB[i*4+1] = *(const uint4*)(xt + pa.y + m*8);
      puB[i*4+2] = *(const uint4*)(xt + pa.z + m*8);
      puB[i*4+3] = *(const uint4*)(xt + pa.w + m*8);
    }
  };
  auto blendA = [&](u16* dst){
    #pragma unroll
    for (int i = 0; i < 2; i++){
      int p = wv*4 + i*2 + kh;
      float f00[8], f01[8], f10[8], f11[8], s[8];
      unpk(puA[i*4+0], f00); unpk(puA[i*4+1], f01);
      unpk(puA[i*4+2], f10); unpk(puA[i*4+3], f11);
      float4 w = pwA[i];
      #pragma unroll
      for (int j = 0; j < 8; j++)
        s[j] = w.x*f00[j] + w.y*f01[j] + w.z*f10[j] + w.w*f11[j];
      *(uint4*)(dst + p*264 + m*8) = pk8(s);
    }
  };
  auto blendB = [&](u16* dst){
    #pragma unroll
    for (int i = 0; i < 2; i++){
      int p = wv*4 + i*2 + kh;
      float f00[8], f01[8], f10[8], f11[8], s[8];
      unpk(puB[i*4+0], f00); unpk(puB[i*4+1], f01);
      unpk(puB[i*4+2], f10); unpk(puB[i*4+3], f11);
      float4 w = pwB[i];
      #pragma unroll
      for (int j = 0; j < 8; j++)
        s[j] = w.x*f00[j] + w.y*f01[j] + w.z*f10[j] + w.w*f11[j];
      *(uint4*)(dst + p*264 + m*8) = pk8(s);
    }
  };
  auto mfma_tap = [&](int tap, const u16* cur){
    int nt0 = wv*2, nt1 = wv*2 + 1;
    int kcg0 = tap*8;
    short8 b0n = *(const short8*)(Bdcn + ((kcg0*8 + nt0)*64 + lane)*8);
    short8 b1n = *(const short8*)(Bdcn + ((kcg0*8 + nt1)*64 + lane)*8);
    #pragma unroll
    for (int kc = 0; kc < 8; kc++){
      short8 b0 = b0n, b1 = b1n;
      if (kc < 7){
        int kcg = tap*8 + kc + 1;
        b0n = *(const short8*)(Bdcn + ((kcg*8 + nt0)*64 + lane)*8);
        b1n = *(const short8*)(Bdcn + ((kcg*8 + nt1)*64 + lane)*8);
      }
      short8 a = *(const short8*)(cur + ln*264 + kc*32 + q4*8);
      acc[0] = mfma16(a, b0, acc[0]);
      acc[1] = mfma16(a, b1, acc[1]);
    }
  };

  // prologue: tap0 -> A (blend immediately into As0), tap1 -> B (in flight)
  prefetchA(0);
  blendA(As0);
  prefetchB(1);
  __syncthreads();

  // taps 0..7 as 4 unrolled even/odd pairs; tap 8 is the tail.
  #pragma unroll
  for (int tp = 0; tp < 4; tp++){
    const int te = tp*2;                // even tap: cur=As0, nxt=As1
    if (te < 7) prefetchA(te + 2);      // A free (its payload tap te was consumed)
    mfma_tap(te, As0);
    blendB(As1);                        // B holds tap te+1
    __syncthreads();

    const int to = te + 1;              // odd tap: cur=As1, nxt=As0
    if (to < 7) prefetchB(to + 2);
    mfma_tap(to, As1);
    blendA(As0);                        // A holds tap to+1 (issued 2 iters ago)
    __syncthreads();
  }
  // tail: tap 8 (data staged in As0 by tap7's blendA)
  mfma_tap(8, As0);
  __syncthreads();

  // epilogue: pack 16px x 32ch (this wave) via LDS, coalesced NHWC store
  #pragma unroll
  for (int nt2 = 0; nt2 < 2; nt2++){
    int ch = wv*32 + nt2*16 + ln;
    float bias = nt2 ? bias1 : bias0;
    #pragma unroll
    for (int r = 0; r < 4; r++){
      int px = q4*4 + r;
      Lp[px*136 + ch] = (u16)(rne(acc[nt2][r] + bias) >> 16);
    }
  }
  __syncthreads();
  {
    int px = t >> 4, cg = t & 15;
    uint4 u = *(const uint4*)(Lp + px*136 + cg*8);
    *(uint4*)(yb + (P0 + px)*128 + cg*8) = u;
  }
  // fused BN1 partial stats from Lp -> sliced atomics (contention 32/addr, single phase)
  {
    int ch = t & 127, hf = t >> 7;
    float s = 0.f, ss = 0.f;
    #pragma unroll
    for (int i = 0; i < 8; i++){
      float v = b2f(Lp[(hf*8 + i)*136 + ch]);
      s += v; ss += v*v;
    }
    red[t] = s;
    red[256 + t] = ss;
    __syncthreads();
    float* slice = p1 + (blk & 31)*256;
    if (t < 128){
      atomicAdd(&slice[t], red[t] + red[t+128]);
    } else {
      int c2 = t - 128;
      atomicAdd(&slice[128 + c2], red[256 + c2] + red[384 + c2]);
    }
  }
}

// ---------------- stage 4: deconv; bn1 finalize from 32 slices, NCHW bf16 out + fused sliced BN2 stats ----------------
// lb(256,4): grid=1024 -> 4 blocks/CU grid-capped; old (256,6) capped VGPR at ~85 for nothing.
__global__ __launch_bounds__(256, 4) void deconv_kernel(const u16* __restrict__ yb,
                                                        const float* __restrict__ p1,
                                                        const float* __restrict__ gamma1,
                                                        const float* __restrict__ beta1,
                                                        const u16* __restrict__ Bup,
                                                        u16* __restrict__ y2n,
                                                        float* __restrict__ p2){
  __shared__ alignas(16) char smem[21568];    // Ls [2][34][136] u16 (18496) | Lo overlay; bnL 1024 @18496 | red2 2048 @19520
  u16* Ls = (u16*)smem;
  u16* Lo = (u16*)smem;
  float2* bnL = (float2*)(smem + 18496);
  float* red2 = (float*)(smem + 19520);
  int blk = xcd_swz(blockIdx.x);        // 1024 = 4b * 128yy * 2half (XCD-chunked)
  int half = blk & 1, yy = (blk >> 1) & 127, b = blk >> 8;
  int pary = yy & 1;
  int hs = (yy - 2 + pary) >> 1;
  int X0 = half * 64, wbase = half*32 - 1;
  int t = threadIdx.x;
  if (t < 128){
    float s = 0.f, ss = 0.f;
    #pragma unroll
    for (int sl = 0; sl < 32; sl++){
      s  += p1[sl*256 + t];
      ss += p1[sl*256 + 128 + t];
    }
    float mean = s * (1.f/16384.f);
    float var  = ss * (1.f/16384.f) - mean*mean;
    float inv  = rsqrtf(var + 1e-5f);
    float sc   = gamma1[t] * inv;
    bnL[t] = make_float2(sc, beta1[t] - mean * sc);
  }
  __syncthreads();
  // stage 2 rows x 34 cols x 128 ch, bn1+relu fused
  #pragma unroll
  for (int it = 0; it < 5; it++){
    int idx = it*256 + t;
    if (idx < 1088){
      int r = idx / 544, rem = idx - r*544;
      int cc = rem >> 4, c16 = rem & 15;
      int hh = hs + r, w_in = wbase + cc;
      uint4 u = make_uint4(0,0,0,0);
      if ((u32)hh < 64u && (u32)w_in < 64u)
        u = *(const uint4*)(yb + (((b*64 + hh)*64 + w_in) << 7) + c16*8);
      float f[8]; unpk(u, f);
      float o[8];
      #pragma unroll
      for (int e = 0; e < 8; e++){
        float2 sc = bnL[c16*8 + e];
        o[e] = fmaxf(0.f, fmaf(sc.x, f[e], sc.y));
      }
      *(uint4*)(Ls + (r*34 + cc)*136 + c16*8) = pk8(o);
    }
  }
  __syncthreads();

  int wv = t >> 6, lane = t & 63;
  int m = lane & 31, kh = lane >> 5;
  int parx = wv & 1, nh = wv >> 1;
  int pp = pary*2 + parx;
  f32x16 acc[2];
  acc[0] = (f32x16){0.f};
  acc[1] = (f32x16){0.f};

  #pragma unroll
  for (int tapd = 0; tapd < 4; tapd++){
    int dyy = tapd >> 1, dxx = tapd & 1;
    const u16* lp = Ls + ((dyy*34 + m + parx + dxx)*136);
    #pragma unroll
    for (int q = 0; q < 8; q++){
      short8 a = *(const short8*)(lp + q*16 + kh*8);
      #pragma unroll
      for (int nt2 = 0; nt2 < 2; nt2++){
        int a4 = nh*2 + nt2;
        short8 bb = *(const short8*)(Bup + ((((pp*32 + tapd*8 + q)*4 + a4)*2 + kh)*32 + m)*8);
        acc[nt2] = mfma32(a, bb, acc[nt2]);
      }
    }
  }
  __syncthreads();                      // done reading Ls; Lo overlays
  #pragma unroll
  for (int nt2 = 0; nt2 < 2; nt2++){
    int ch = (nh*2 + nt2)*32 + m;
    #pragma unroll
    for (int r = 0; r < 16; r++){
      int mrow = (r & 3) + 8*(r >> 2) + 4*kh;
      int xl = parx + 2*mrow;
      Lo[xl*136 + ch] = (u16)(rne(acc[nt2][r]) >> 16);
    }
  }
  __syncthreads();
  // readout: NCHW bf16, 64B contiguous per thread
  {
    int ch = t >> 1, xh = t & 1;
    u16* gp = y2n + ((b*128 + ch)*128 + yy)*128 + X0 + xh*32;
    #pragma unroll
    for (int g = 0; g < 4; g++){
      u32 r4[4];
      #pragma unroll
      for (int e = 0; e < 4; e++){
        u32 lo = Lo[(xh*32 + g*8 + 2*e)*136 + ch];
        u32 hi = Lo[(xh*32 + g*8 + 2*e + 1)*136 + ch];
        r4[e] = lo | (hi << 16);
      }
      *(uint4*)(gp + g*8) = make_uint4(r4[0], r4[1], r4[2], r4[3]);
    }
  }
  // fused BN2 partial stats from Lo -> sliced atomics (contention 32/addr, single phase)
  {
    int ch = t & 127, hf = t >> 7;
    float s = 0.f, ss = 0.f;
    #pragma unroll
    for (int i = 0; i < 32; i++){
      float v = b2f(Lo[(hf*32 + i)*136 + ch]);
      s += v; ss += v*v;
    }
    red2[t] = s;
    red2[256 + t] = ss;
    __syncthreads();
    float* slice = p2 + (blk & 31)*256;
    if (t < 128){
      atomicAdd(&slice[t], red2[t] + red2[t+128]);
    } else {
      int c2 = t - 128;
      atomicAdd(&slice[128 + c2], red2[256 + c2] + red2[384 + c2]);
    }
  }
}

// ---------------- stage 5: BN2 finalize (slice-reduce in LDS prologue) + ReLU elementwise NCHW, f32 out ----------------
__global__ __launch_bounds__(256) void final_kernel(const u16* __restrict__ y2n,
                                                    const float* __restrict__ p2,
                                                    const float* __restrict__ gamma2,
                                                    const float* __restrict__ beta2,
                                                    float* __restrict__ outp){
  __shared__ float2 scsh[128];
  int t = threadIdx.x;
  if (t < 128){
    float s = 0.f, ss = 0.f;
    #pragma unroll
    for (int sl = 0; sl < 32; sl++){
      s  += p2[sl*256 + t];
      ss += p2[sl*256 + 128 + t];
    }
    float mean = s * (1.f/65536.f);
    float var  = ss * (1.f/65536.f) - mean*mean;
    float inv  = rsqrtf(var + 1e-5f);
    float scx  = gamma2[t] * inv;
    scsh[t] = make_float2(scx, beta2[t] - mean * scx);
  }
  __syncthreads();
  int gid0 = blockIdx.x*256 + t;        // 1024 blocks, 4 grid-stride iters
  #pragma unroll
  for (int it = 0; it < 4; it++){
    int idx = (gid0 + it*262144) * 8;
    int ch = (idx >> 14) & 127;
    float2 sc = scsh[ch];
    uint4 u = *(const uint4*)(y2n + idx);
    float f[8]; unpk(u, f);
    float4 o0, o1;
    o0.x = fmaxf(0.f, fmaf(sc.x, f[0], sc.y));
    o0.y = fmaxf(0.f, fmaf(sc.x, f[1], sc.y));
    o0.z = fmaxf(0.f, fmaf(sc.x, f[2], sc.y));
    o0.w = fmaxf(0.f, fmaf(sc.x, f[3], sc.y));
    o1.x = fmaxf(0.f, fmaf(sc.x, f[4], sc.y));
    o1.y = fmaxf(0.f, fmaf(sc.x, f[5], sc.y));
    o1.z = fmaxf(0.f, fmaf(sc.x, f[6], sc.y));
    o1.w = fmaxf(0.f, fmaf(sc.x, f[7], sc.y));
    *(float4*)(outp + idx)     = o0;
    *(float4*)(outp + idx + 4) = o1;
  }
}

extern "C" void kernel_launch(void* const* d_in, const int* in_sizes, int n_in,
                              void* d_out, int out_size, void* d_ws, size_t ws_size,
                              hipStream_t stream) {
  const float* x      = (const float*)d_in[0];
  const float* w_off  = (const float*)d_in[1];
  const float* b_off  = (const float*)d_in[2];
  const float* w_dcn  = (const float*)d_in[3];
  const float* b_dcn  = (const float*)d_in[4];
  const float* gamma1 = (const float*)d_in[5];
  const float* beta1  = (const float*)d_in[6];
  const float* w_up   = (const float*)d_in[7];
  const float* gamma2 = (const float*)d_in[8];
  const float* beta2  = (const float*)d_in[9];

  char* ws = (char*)d_ws;
  u16*   xt    = (u16*)(ws + OFF_XT);
  float* om    = (float*)(ws + OFF_OM);
  u16*   yb    = (u16*)(ws + OFF_Y);
  u16*   y2n   = (u16*)(ws + OFF_Y2);
  u16*   Boff  = (u16*)(ws + OFF_BOFF);
  u16*   Bdcn  = (u16*)(ws + OFF_BDCN);
  u16*   Bup   = (u16*)(ws + OFF_BUP);
  float* p1    = (float*)(ws + OFF_P1);
  float* p2    = (float*)(ws + OFF_P2);

  prep_transpose_kernel<<<2177, 256, 0, stream>>>(x, xt, w_off, w_dcn, w_up, Boff, Bdcn, Bup, p1);
  convoff_kernel<<<1024, 256, 0, stream>>>(xt, Boff, b_off, om);
  mdcn_kernel<<<1024, 256, 0, stream>>>(xt, om, Bdcn, b_dcn, yb, p1);
  deconv_kernel<<<1024, 256, 0, stream>>>(yb, p1, gamma1, beta1, Bup, y2n, p2);
  final_kernel<<<1024, 256, 0, stream>>>(y2n, p2, gamma2, beta2, (float*)d_out);
}

// Round 11
// 161.666 us; speedup vs baseline: 1.0205x; 1.0205x over previous
//
#include <hip/hip_runtime.h>
#include <hip/hip_bf16.h>

typedef __attribute__((ext_vector_type(8))) short short8;
typedef __attribute__((ext_vector_type(4))) float f32x4;
typedef __attribute__((ext_vector_type(16))) float f32x16;
typedef unsigned short u16;
typedef unsigned int u32;

// ---------------- workspace layout (bytes) ----------------
#define OFF_XT      0u          // x NHWC bf16: 4*64*64*256 = 8388608 B
#define OFF_OM      8388608u    // offsets fp32: 16384*32*4  = 2097152 B
#define OFF_Y       10485760u   // mdcn out NHWC bf16: 16384*128*2 = 4194304 B
#define OFF_Y2      14680064u   // deconv out NCHW bf16: 4*128*128*128*2 = 16777216 B
#define OFF_BOFF    31457280u   // Boff16 [72][2][64][8] bf16 = 147456 B
#define OFF_BDCN    31604736u   // Bdcn16 [72][8][64][8] bf16 = 589824 B
#define OFF_BUP     32194560u   // Bup'  [4][32][4][2][32][8] bf16 = 524288 B
#define OFF_P1      32718848u   // BN1 partials [32 slice][256] f32 = 32768 B
#define OFF_P2      32751616u   // BN2 partials [32 slice][256] f32 = 32768 B
// end: 32784384 B

__device__ __forceinline__ float lo2f(u32 u){ u32 v = u << 16; float f; __builtin_memcpy(&f, &v, 4); return f; }
__device__ __forceinline__ float hi2f(u32 u){ u32 v = u & 0xffff0000u; float f; __builtin_memcpy(&f, &v, 4); return f; }
__device__ __forceinline__ float b2f(u16 v){ u32 u = ((u32)v) << 16; float f; __builtin_memcpy(&f, &u, 4); return f; }
__device__ __forceinline__ u16 f2b(float f){ __hip_bfloat16 h = __float2bfloat16(f); u16 r; __builtin_memcpy(&r, &h, 2); return r; }
// fast RNE f32->bf16 (finite values only)
__device__ __forceinline__ u32 rne(float f){ u32 u; __builtin_memcpy(&u, &f, 4); return u + 0x7FFFu + ((u >> 16) & 1u); }
__device__ __forceinline__ u32 pk2(float f0, float f1){ return (rne(f0) >> 16) | (rne(f1) & 0xFFFF0000u); }

__device__ __forceinline__ f32x4 mfma16(short8 a, short8 b, f32x4 c){
  return __builtin_amdgcn_mfma_f32_16x16x32_bf16(a, b, c, 0, 0, 0);
}
__device__ __forceinline__ f32x16 mfma32(short8 a, short8 b, f32x16 c){
  return __builtin_amdgcn_mfma_f32_32x32x16_bf16(a, b, c, 0, 0, 0);
}
__device__ __forceinline__ void unpk(uint4 u, float* f){
  f[0]=lo2f(u.x); f[1]=hi2f(u.x); f[2]=lo2f(u.y); f[3]=hi2f(u.y);
  f[4]=lo2f(u.z); f[5]=hi2f(u.z); f[6]=lo2f(u.w); f[7]=hi2f(u.w);
}
__device__ __forceinline__ uint4 pk8(const float* f){
  uint4 r;
  r.x = pk2(f[0], f[1]); r.y = pk2(f[2], f[3]);
  r.z = pk2(f[4], f[5]); r.w = pk2(f[6], f[7]);
  return r;
}
// XCD-chunked bijective swizzle for 1024-block grids (1024 % 8 == 0):
// each XCD gets 128 CONSECUTIVE logical tiles -> halo rows shared within one L2.
__device__ __forceinline__ int xcd_swz(int blk0){ return ((blk0 & 7) << 7) | (blk0 >> 3); }

// ---------------- kernel 1: weight reorg + transpose + partials-zero (one dispatch) ----------------
__global__ __launch_bounds__(256) void prep_transpose_kernel(const float* __restrict__ x,
                                                             u16* __restrict__ xt,
                                                             const float* __restrict__ w_off,
                                                             const float* __restrict__ w_dcn,
                                                             const float* __restrict__ w_up,
                                                             u16* __restrict__ Boff,
                                                             u16* __restrict__ Bdcn,
                                                             u16* __restrict__ Bup,
                                                             float* __restrict__ pz){
  __shared__ u16 Ls[64][65];
  int blk = blockIdx.x;
  int t = threadIdx.x;
  if (blk >= 2176){
    // ---- zero BN partials p1+p2 (16384 f32 = 4096 float4) ----
    float4* p4 = (float4*)pz;
    #pragma unroll
    for (int i = 0; i < 16; i++)
      p4[t*16 + i] = make_float4(0.f, 0.f, 0.f, 0.f);
    return;
  }
  if (blk < 1024){
    // ---- transpose: 1024 = 4b * 64h * 4cb; float4 reads, uint2 writes (G13) ----
    int cb = blk & 3, h = (blk >> 2) & 63, b = blk >> 8;
    int c0 = cb * 64;
    {
      int w4 = (t & 15) * 4;
      #pragma unroll
      for (int i = 0; i < 4; i++){
        int c = (t >> 4) + 16*i;
        float4 v = *(const float4*)(x + (((b*256 + c0 + c)*64 + h)*64 + w4));
        Ls[c][w4+0] = f2b(v.x);
        Ls[c][w4+1] = f2b(v.y);
        Ls[c][w4+2] = f2b(v.z);
        Ls[c][w4+3] = f2b(v.w);
      }
    }
    __syncthreads();
    #pragma unroll
    for (int i = 0; i < 4; i++){
      int idx = t + i*256;
      int w = idx >> 4, cc = (idx & 15) * 4;
      u32 a0 = Ls[cc+0][w], a1 = Ls[cc+1][w];
      u32 a2 = Ls[cc+2][w], a3 = Ls[cc+3][w];
      uint2 val = make_uint2(a0 | (a1 << 16), a2 | (a3 << 16));
      *(uint2*)(xt + (((b*64 + h)*64 + w) << 8) + c0 + cc) = val;
    }
    return;
  }
  // ---- prep: 1152 blocks ----
  int i = (blk - 1024) * 256 + t;
  if (i < 72*2*64*8){
    int j = i & 7, lane = (i >> 3) & 63, nt = (i >> 9) & 1, kc = i >> 10;
    int n = nt*16 + (lane & 15);
    int k = kc*32 + ((lane >> 4) & 3)*8 + j, tap = k >> 8, c = k & 255;
    int ky = tap / 3, kx = tap - ky*3;
    u16 v = 0;
    if (n < 27) v = f2b(w_off[((n*256 + c)*3 + ky)*3 + kx]);
    Boff[i] = v;
  }
  if (i < 72*8*64*8){
    int j = i & 7, lane = (i >> 3) & 63, nt = (i >> 9) & 7, kc = i >> 12;
    int o = nt*16 + (lane & 15);
    int k = kc*32 + ((lane >> 4) & 3)*8 + j, tap = k >> 8, c = k & 255;
    int ky = tap / 3, kx = tap - ky*3;
    Bdcn[i] = f2b(w_dcn[((o*256 + c)*3 + ky)*3 + kx]);
  }
  if (i < 4*32*4*2*32*8){
    int j = i & 7, n = (i >> 3) & 31, kh = (i >> 8) & 1, a4 = (i >> 9) & 3;
    int kc = (i >> 11) & 31, pp = i >> 16;
    int k = kc*16 + kh*8 + j, tapd = k >> 7, c = k & 127;
    int o = a4*32 + n;
    int py = pp >> 1, px = pp & 1, dy = tapd >> 1, dx = tapd & 1;
    Bup[i] = f2b(w_up[((c*128 + o)*4 + (3-(py+2*dy)))*4 + (3-(px+2*dx))]);
  }
}

// ---------------- stage 1: offset conv; dbuf 3-phase pipeline, 4-wave K-split (r9-verified lb(256,8)) ----------------
__global__ __launch_bounds__(256, 8) void convoff_kernel(const u16* __restrict__ xt,
                                                         const u16* __restrict__ Boff,
                                                         const float* __restrict__ b_off,
                                                         float* __restrict__ om){
  __shared__ alignas(16) char smem[16896];    // As dbuf 2x[16px][264]; Ys overlays
  u16* As0 = (u16*)smem;
  u16* As1 = (u16*)(smem + 8448);
  float* Ys = (float*)smem;                   // [4][16][36] = 9216 B (after final barrier)
  int blk = xcd_swz(blockIdx.x);        // 1024 = 4b * 64h * 4wt (XCD-chunked)
  int wt = blk & 3, h = (blk >> 2) & 63, b = blk >> 8;
  int w0 = wt * 16;
  int P0 = (b*64 + h)*64 + w0;
  int t = threadIdx.x;
  int wv = t >> 6, lane = t & 63;
  int ln = lane & 15, q4 = (lane >> 4) & 3;
  int spx = t >> 5, sc16a = t & 31;     // staging: px = spx(+8), c16
  f32x4 acc[2];
  acc[0] = (f32x4){0.f,0.f,0.f,0.f};
  acc[1] = (f32x4){0.f,0.f,0.f,0.f};
  uint4 pf[2];

  // prefetch + stage tap 0
  {
    int ky = -1, kx = -1;
    #pragma unroll
    for (int it = 0; it < 2; it++){
      int px = spx + it*8;
      int y = h + ky, xw = w0 + px + kx;
      pf[it] = make_uint4(0,0,0,0);
      if ((u32)y < 64u && (u32)xw < 64u)
        pf[it] = *(const uint4*)(xt + (((b*64 + y)*64 + xw) << 8) + sc16a*8);
    }
    #pragma unroll
    for (int it = 0; it < 2; it++)
      *(uint4*)(As0 + (spx + it*8)*264 + sc16a*8) = pf[it];
  }
  __syncthreads();

  for (int tap = 0; tap < 9; tap++){
    const u16* cur = (tap & 1) ? As1 : As0;
    u16* nxt = (tap & 1) ? As0 : As1;
    if (tap < 8){
      int tn = tap + 1;
      int ky = tn/3 - 1, kx = tn - (tn/3)*3 - 1;
      #pragma unroll
      for (int it = 0; it < 2; it++){
        int px = spx + it*8;
        int y = h + ky, xw = w0 + px + kx;
        pf[it] = make_uint4(0,0,0,0);
        if ((u32)y < 64u && (u32)xw < 64u)
          pf[it] = *(const uint4*)(xt + (((b*64 + y)*64 + xw) << 8) + sc16a*8);
      }
    }
    #pragma unroll
    for (int q = 0; q < 2; q++){
      int kcl = wv*2 + q;
      int kcg = tap*8 + kcl;
      short8 a = *(const short8*)(cur + ln*264 + kcl*32 + q4*8);
      #pragma unroll
      for (int nt = 0; nt < 2; nt++){
        short8 bb = *(const short8*)(Boff + ((kcg*2 + nt)*64 + lane)*8);
        acc[nt] = mfma16(a, bb, acc[nt]);
      }
    }
    if (tap < 8){
      #pragma unroll
      for (int it = 0; it < 2; it++)
        *(uint4*)(nxt + (spx + it*8)*264 + sc16a*8) = pf[it];
    }
    __syncthreads();
  }
  // K-split reduction (Ys overlays As; loop's final barrier protects)
  #pragma unroll
  for (int nt = 0; nt < 2; nt++)
    #pragma unroll
    for (int r = 0; r < 4; r++)
      Ys[(wv*16 + q4*4 + r)*36 + nt*16 + ln] = acc[nt][r];
  __syncthreads();
  {
    int px = t >> 4, s = t & 15;
    #pragma unroll
    for (int half = 0; half < 2; half++){
      int n = s + half*16;
      if (n < 27){
        float sum = Ys[(px)*36 + n] + Ys[(16 + px)*36 + n]
                  + Ys[(32 + px)*36 + n] + Ys[(48 + px)*36 + n] + b_off[n];
        om[(P0 + px)*32 + n] = sum;
      }
    }
  }
}

// ---------------- stage 2: mdcn v13: 2-tap-deep gather pipeline, NAMED register sets (r9-verified) ----------------
__global__ __launch_bounds__(256, 4) void mdcn_kernel(const u16* __restrict__ xt,
                                                      const float* __restrict__ om,
                                                      const u16* __restrict__ Bdcn,
                                                      const float* __restrict__ b_dcn,
                                                      u16* __restrict__ yb,
                                                      float* __restrict__ p1){
  __shared__ alignas(16) char smem[23552];
  u16* As0 = (u16*)smem;
  u16* As1 = (u16*)(smem + 8448);
  float* Ptab = (float*)(smem + 16896);       // [16 px][9 tap][8]: a00,a01,a10,a11,w00,w01,w10,w11
  u16* Lp = (u16*)(smem + 8448);              // [16][136] epilogue overlay of As1
  float* red = (float*)(smem + 21504);        // [512] stats reduce (disjoint)
  int blk = xcd_swz(blockIdx.x);        // 1024 = 4b * 64h * 4wt (XCD-chunked)
  int wt = blk & 3, h = (blk >> 2) & 63, b = blk >> 8;
  int w0 = wt * 16;
  int P0 = (b*64 + h)*64 + w0;
  int t = threadIdx.x;
  int wv = t >> 6, lane = t & 63;
  int m = lane & 31, kh = lane >> 5;
  int ln = lane & 15, q4 = (lane >> 4) & 3;
  float bias0 = b_dcn[wv*32 + ln];
  float bias1 = b_dcn[wv*32 + 16 + ln];

  // ---- build param table (one thread per (px,tap)) ----
  if (t < 144){
    int px = t / 9, tap = t - (t/9)*9;
    int ky = tap / 3, kx = tap - ky*3;
    const float* omp = om + (P0 + px)*32;
    float dy  = omp[2*tap];
    float dxv = omp[2*tap + 1];
    float mk  = 1.f / (1.f + __expf(-omp[18 + tap]));
    float ys = (float)(h - 1 + ky) + dy;
    float xs = (float)(w0 + px - 1 + kx) + dxv;
    float y0f = floorf(ys), x0f = floorf(xs);
    float ly = ys - y0f, lx = xs - x0f;
    int y0 = (int)y0f, x0 = (int)x0f;
    bool vy0 = (u32)y0 < 64u, vy1 = (u32)(y0+1) < 64u;
    bool vx0 = (u32)x0 < 64u, vx1 = (u32)(x0+1) < 64u;
    int ya = min(max(y0, 0), 63),   ybr_ = min(max(y0+1, 0), 63);
    int xa = min(max(x0, 0), 63),   xb = min(max(x0+1, 0), 63);
    u32 a00 = (u32)(((b*64 + ya)*64 + xa) << 8);
    u32 a01 = (u32)(((b*64 + ya)*64 + xb) << 8);
    u32 a10 = (u32)(((b*64 + ybr_)*64 + xa) << 8);
    u32 a11 = (u32)(((b*64 + ybr_)*64 + xb) << 8);
    float w00 = (vy0 && vx0) ? (1.f-ly)*(1.f-lx)*mk : 0.f;
    float w01 = (vy0 && vx1) ? (1.f-ly)*lx*mk       : 0.f;
    float w10 = (vy1 && vx0) ? ly*(1.f-lx)*mk       : 0.f;
    float w11 = (vy1 && vx1) ? ly*lx*mk             : 0.f;
    float* P = Ptab + t*8;
    ((u32*)P)[0] = a00; ((u32*)P)[1] = a01; ((u32*)P)[2] = a10; ((u32*)P)[3] = a11;
    P[4] = w00; P[5] = w01; P[6] = w10; P[7] = w11;
  }
  __syncthreads();

  f32x4 acc[2];
  acc[0] = (f32x4){0.f,0.f,0.f,0.f};
  acc[1] = (f32x4){0.f,0.f,0.f,0.f};
  uint4 puA[8], puB[8];     // two in-flight gather sets, NAMED (never passed via pointer)
  float4 pwA[2], pwB[2];

  auto prefetchA = [&](int tap){
    #pragma unroll
    for (int i = 0; i < 2; i++){
      int p = wv*4 + i*2 + kh;
      const float* P = Ptab + (p*9 + tap)*8;
      uint4 pa = *(const uint4*)P;
      pwA[i] = *(const float4*)(P + 4);
      puA[i*4+0] = *(const uint4*)(xt + pa.x + m*8);
      puA[i*4+1] = *(const uint4*)(xt + pa.y + m*8);
      puA[i*4+2] = *(const uint4*)(xt + pa.z + m*8);
      puA[i*4+3] = *(const uint4*)(xt + pa.w + m*8);
    }
  };
  auto prefetchB = [&](int tap){
    #pragma unroll
    for (int i = 0; i < 2; i++){
      int p = wv*4 + i*2 + kh;
      const float* P = Ptab + (p*9 + tap)*8;
      uint4 pa = *(const uint4*)P;
      pwB[i] = *(const float4*)(P + 4);
      puB[i*4+0] = *(const uint4*)(xt + pa.x + m*8);
      puB[i*4+1] = *(const uint4*)(xt + pa.y + m*8);
      puB[i*4+2] = *(const uint4*)(xt + pa.z + m*8);
      puB[i*4+3] = *(const uint4*)(xt + pa.w + m*8);
    }
  };
  auto blendA = [&](u16* dst){
    #pragma unroll
    for (int i = 0; i < 2; i++){
      int p = wv*4 + i*2 + kh;
      float f00[8], f01[8], f10[8], f11[8], s[8];
      unpk(puA[i*4+0], f00); unpk(puA[i*4+1], f01);
      unpk(puA[i*4+2], f10); unpk(puA[i*4+3], f11);
      float4 w = pwA[i];
      #pragma unroll
      for (int j = 0; j < 8; j++)
        s[j] = w.x*f00[j] + w.y*f01[j] + w.z*f10[j] + w.w*f11[j];
      *(uint4*)(dst + p*264 + m*8) = pk8(s);
    }
  };
  auto blendB = [&](u16* dst){
    #pragma unroll
    for (int i = 0; i < 2; i++){
      int p = wv*4 + i*2 + kh;
      float f00[8], f01[8], f10[8], f11[8], s[8];
      unpk(puB[i*4+0], f00); unpk(puB[i*4+1], f01);
      unpk(puB[i*4+2], f10); unpk(puB[i*4+3], f11);
      float4 w = pwB[i];
      #pragma unroll
      for (int j = 0; j < 8; j++)
        s[j] = w.x*f00[j] + w.y*f01[j] + w.z*f10[j] + w.w*f11[j];
      *(uint4*)(dst + p*264 + m*8) = pk8(s);
    }
  };
  auto mfma_tap = [&](int tap, const u16* cur){
    int nt0 = wv*2, nt1 = wv*2 + 1;
    int kcg0 = tap*8;
    short8 b0n = *(const short8*)(Bdcn + ((kcg0*8 + nt0)*64 + lane)*8);
    short8 b1n = *(const short8*)(Bdcn + ((kcg0*8 + nt1)*64 + lane)*8);
    #pragma unroll
    for (int kc = 0; kc < 8; kc++){
      short8 b0 = b0n, b1 = b1n;
      if (kc < 7){
        int kcg = tap*8 + kc + 1;
        b0n = *(const short8*)(Bdcn + ((kcg*8 + nt0)*64 + lane)*8);
        b1n = *(const short8*)(Bdcn + ((kcg*8 + nt1)*64 + lane)*8);
      }
      short8 a = *(const short8*)(cur + ln*264 + kc*32 + q4*8);
      acc[0] = mfma16(a, b0, acc[0]);
      acc[1] = mfma16(a, b1, acc[1]);
    }
  };

  // prologue: tap0 -> A (blend immediately into As0), tap1 -> B (in flight)
  prefetchA(0);
  blendA(As0);
  prefetchB(1);
  __syncthreads();

  // taps 0..7 as 4 unrolled even/odd pairs; tap 8 is the tail.
  #pragma unroll
  for (int tp = 0; tp < 4; tp++){
    const int te = tp*2;                // even tap: cur=As0, nxt=As1
    if (te < 7) prefetchA(te + 2);      // A free (its payload tap te was consumed)
    mfma_tap(te, As0);
    blendB(As1);                        // B holds tap te+1
    __syncthreads();

    const int to = te + 1;              // odd tap: cur=As1, nxt=As0
    if (to < 7) prefetchB(to + 2);
    mfma_tap(to, As1);
    blendA(As0);                        // A holds tap to+1 (issued 2 iters ago)
    __syncthreads();
  }
  // tail: tap 8 (data staged in As0 by tap7's blendA)
  mfma_tap(8, As0);
  __syncthreads();

  // epilogue: pack 16px x 32ch (this wave) via LDS, coalesced NHWC store
  #pragma unroll
  for (int nt2 = 0; nt2 < 2; nt2++){
    int ch = wv*32 + nt2*16 + ln;
    float bias = nt2 ? bias1 : bias0;
    #pragma unroll
    for (int r = 0; r < 4; r++){
      int px = q4*4 + r;
      Lp[px*136 + ch] = (u16)(rne(acc[nt2][r] + bias) >> 16);
    }
  }
  __syncthreads();
  {
    int px = t >> 4, cg = t & 15;
    uint4 u = *(const uint4*)(Lp + px*136 + cg*8);
    *(uint4*)(yb + (P0 + px)*128 + cg*8) = u;
  }
  // fused BN1 partial stats from Lp -> sliced atomics (contention 32/addr, single phase)
  {
    int ch = t & 127, hf = t >> 7;
    float s = 0.f, ss = 0.f;
    #pragma unroll
    for (int i = 0; i < 8; i++){
      float v = b2f(Lp[(hf*8 + i)*136 + ch]);
      s += v; ss += v*v;
    }
    red[t] = s;
    red[256 + t] = ss;
    __syncthreads();
    float* slice = p1 + (blk & 31)*256;
    if (t < 128){
      atomicAdd(&slice[t], red[t] + red[t+128]);
    } else {
      int c2 = t - 128;
      atomicAdd(&slice[128 + c2], red[256 + c2] + red[384 + c2]);
    }
  }
}

// ---------------- stage 4: deconv; bn1 finalize from 32 slices, NCHW bf16 out + fused sliced BN2 stats (r9-verified lb(256,6)) ----------------
__global__ __launch_bounds__(256, 6) void deconv_kernel(const u16* __restrict__ yb,
                                                        const float* __restrict__ p1,
                                                        const float* __restrict__ gamma1,
                                                        const float* __restrict__ beta1,
                                                        const u16* __restrict__ Bup,
                                                        u16* __restrict__ y2n,
                                                        float* __restrict__ p2){
  __shared__ alignas(16) char smem[21568];    // Ls [2][34][136] u16 (18496) | Lo overlay; bnL 1024 @18496 | red2 2048 @19520
  u16* Ls = (u16*)smem;
  u16* Lo = (u16*)smem;
  float2* bnL = (float2*)(smem + 18496);
  float* red2 = (float*)(smem + 19520);
  int blk = xcd_swz(blockIdx.x);        // 1024 = 4b * 128yy * 2half (XCD-chunked)
  int half = blk & 1, yy = (blk >> 1) & 127, b = blk >> 8;
  int pary = yy & 1;
  int hs = (yy - 2 + pary) >> 1;
  int X0 = half * 64, wbase = half*32 - 1;
  int t = threadIdx.x;
  if (t < 128){
    float s = 0.f, ss = 0.f;
    #pragma unroll
    for (int sl = 0; sl < 32; sl++){
      s  += p1[sl*256 + t];
      ss += p1[sl*256 + 128 + t];
    }
    float mean = s * (1.f/16384.f);
    float var  = ss * (1.f/16384.f) - mean*mean;
    float inv  = rsqrtf(var + 1e-5f);
    float sc   = gamma1[t] * inv;
    bnL[t] = make_float2(sc, beta1[t] - mean * sc);
  }
  __syncthreads();
  // stage 2 rows x 34 cols x 128 ch, bn1+relu fused
  #pragma unroll
  for (int it = 0; it < 5; it++){
    int idx = it*256 + t;
    if (idx < 1088){
      int r = idx / 544, rem = idx - r*544;
      int cc = rem >> 4, c16 = rem & 15;
      int hh = hs + r, w_in = wbase + cc;
      uint4 u = make_uint4(0,0,0,0);
      if ((u32)hh < 64u && (u32)w_in < 64u)
        u = *(const uint4*)(yb + (((b*64 + hh)*64 + w_in) << 7) + c16*8);
      float f[8]; unpk(u, f);
      float o[8];
      #pragma unroll
      for (int e = 0; e < 8; e++){
        float2 sc = bnL[c16*8 + e];
        o[e] = fmaxf(0.f, fmaf(sc.x, f[e], sc.y));
      }
      *(uint4*)(Ls + (r*34 + cc)*136 + c16*8) = pk8(o);
    }
  }
  __syncthreads();

  int wv = t >> 6, lane = t & 63;
  int m = lane & 31, kh = lane >> 5;
  int parx = wv & 1, nh = wv >> 1;
  int pp = pary*2 + parx;
  f32x16 acc[2];
  acc[0] = (f32x16){0.f};
  acc[1] = (f32x16){0.f};

  #pragma unroll
  for (int tapd = 0; tapd < 4; tapd++){
    int dyy = tapd >> 1, dxx = tapd & 1;
    const u16* lp = Ls + ((dyy*34 + m + parx + dxx)*136);
    #pragma unroll
    for (int q = 0; q < 8; q++){
      short8 a = *(const short8*)(lp + q*16 + kh*8);
      #pragma unroll
      for (int nt2 = 0; nt2 < 2; nt2++){
        int a4 = nh*2 + nt2;
        short8 bb = *(const short8*)(Bup + ((((pp*32 + tapd*8 + q)*4 + a4)*2 + kh)*32 + m)*8);
        acc[nt2] = mfma32(a, bb, acc[nt2]);
      }
    }
  }
  __syncthreads();                      // done reading Ls; Lo overlays
  #pragma unroll
  for (int nt2 = 0; nt2 < 2; nt2++){
    int ch = (nh*2 + nt2)*32 + m;
    #pragma unroll
    for (int r = 0; r < 16; r++){
      int mrow = (r & 3) + 8*(r >> 2) + 4*kh;
      int xl = parx + 2*mrow;
      Lo[xl*136 + ch] = (u16)(rne(acc[nt2][r]) >> 16);
    }
  }
  __syncthreads();
  // readout: NCHW bf16, 64B contiguous per thread
  {
    int ch = t >> 1, xh = t & 1;
    u16* gp = y2n + ((b*128 + ch)*128 + yy)*128 + X0 + xh*32;
    #pragma unroll
    for (int g = 0; g < 4; g++){
      u32 r4[4];
      #pragma unroll
      for (int e = 0; e < 4; e++){
        u32 lo = Lo[(xh*32 + g*8 + 2*e)*136 + ch];
        u32 hi = Lo[(xh*32 + g*8 + 2*e + 1)*136 + ch];
        r4[e] = lo | (hi << 16);
      }
      *(uint4*)(gp + g*8) = make_uint4(r4[0], r4[1], r4[2], r4[3]);
    }
  }
  // fused BN2 partial stats from Lo -> sliced atomics (contention 32/addr, single phase)
  {
    int ch = t & 127, hf = t >> 7;
    float s = 0.f, ss = 0.f;
    #pragma unroll
    for (int i = 0; i < 32; i++){
      float v = b2f(Lo[(hf*32 + i)*136 + ch]);
      s += v; ss += v*v;
    }
    red2[t] = s;
    red2[256 + t] = ss;
    __syncthreads();
    float* slice = p2 + (blk & 31)*256;
    if (t < 128){
      atomicAdd(&slice[t], red2[t] + red2[t+128]);
    } else {
      int c2 = t - 128;
      atomicAdd(&slice[128 + c2], red2[256 + c2] + red2[384 + c2]);
    }
  }
}

// ---------------- stage 5: BN2 finalize (slice-reduce in LDS prologue) + ReLU elementwise NCHW, f32 out ----------------
__global__ __launch_bounds__(256) void final_kernel(const u16* __restrict__ y2n,
                                                    const float* __restrict__ p2,
                                                    const float* __restrict__ gamma2,
                                                    const float* __restrict__ beta2,
                                                    float* __restrict__ outp){
  __shared__ float2 scsh[128];
  int t = threadIdx.x;
  if (t < 128){
    float s = 0.f, ss = 0.f;
    #pragma unroll
    for (int sl = 0; sl < 32; sl++){
      s  += p2[sl*256 + t];
      ss += p2[sl*256 + 128 + t];
    }
    float mean = s * (1.f/65536.f);
    float var  = ss * (1.f/65536.f) - mean*mean;
    float inv  = rsqrtf(var + 1e-5f);
    float scx  = gamma2[t] * inv;
    scsh[t] = make_float2(scx, beta2[t] - mean * scx);
  }
  __syncthreads();
  int gid0 = blockIdx.x*256 + t;        // 1024 blocks, 4 grid-stride iters
  #pragma unroll
  for (int it = 0; it < 4; it++){
    int idx = (gid0 + it*262144) * 8;
    int ch = (idx >> 14) & 127;
    float2 sc = scsh[ch];
    uint4 u = *(const uint4*)(y2n + idx);
    float f[8]; unpk(u, f);
    float4 o0, o1;
    o0.x = fmaxf(0.f, fmaf(sc.x, f[0], sc.y));
    o0.y = fmaxf(0.f, fmaf(sc.x, f[1], sc.y));
    o0.z = fmaxf(0.f, fmaf(sc.x, f[2], sc.y));
    o0.w = fmaxf(0.f, fmaf(sc.x, f[3], sc.y));
    o1.x = fmaxf(0.f, fmaf(sc.x, f[4], sc.y));
    o1.y = fmaxf(0.f, fmaf(sc.x, f[5], sc.y));
    o1.z = fmaxf(0.f, fmaf(sc.x, f[6], sc.y));
    o1.w = fmaxf(0.f, fmaf(sc.x, f[7], sc.y));
    *(float4*)(outp + idx)     = o0;
    *(float4*)(outp + idx + 4) = o1;
  }
}

extern "C" void kernel_launch(void* const* d_in, const int* in_sizes, int n_in,
                              void* d_out, int out_size, void* d_ws, size_t ws_size,
                              hipStream_t stream) {
  const float* x      = (const float*)d_in[0];
  const float* w_off  = (const float*)d_in[1];
  const float* b_off  = (const float*)d_in[2];
  const float* w_dcn  = (const float*)d_in[3];
  const float* b_dcn  = (const float*)d_in[4];
  const float* gamma1 = (const float*)d_in[5];
  const float* beta1  = (const float*)d_in[6];
  const float* w_up   = (const float*)d_in[7];
  const float* gamma2 = (const float*)d_in[8];
  const float* beta2  = (const float*)d_in[9];

  char* ws = (char*)d_ws;
  u16*   xt    = (u16*)(ws + OFF_XT);
  float* om    = (float*)(ws + OFF_OM);
  u16*   yb    = (u16*)(ws + OFF_Y);
  u16*   y2n   = (u16*)(ws + OFF_Y2);
  u16*   Boff  = (u16*)(ws + OFF_BOFF);
  u16*   Bdcn  = (u16*)(ws + OFF_BDCN);
  u16*   Bup   = (u16*)(ws + OFF_BUP);
  float* p1    = (float*)(ws + OFF_P1);
  float* p2    = (float*)(ws + OFF_P2);

  prep_transpose_kernel<<<2177, 256, 0, stream>>>(x, xt, w_off, w_dcn, w_up, Boff, Bdcn, Bup, p1);
  convoff_kernel<<<1024, 256, 0, stream>>>(xt, Boff, b_off, om);
  mdcn_kernel<<<1024, 256, 0, stream>>>(xt, om, Bdcn, b_dcn, yb, p1);
  deconv_kernel<<<1024, 256, 0, stream>>>(yb, p1, gamma1, beta1, Bup, y2n, p2);
  final_kernel<<<1024, 256, 0, stream>>>(y2n, p2, gamma2, beta2, (float*)d_out);
}